// Round 5
// baseline (356.834 us; speedup 1.0000x reference)
//
#include <hip/hip_runtime.h>

typedef __attribute__((ext_vector_type(4)))  float f32x4;
typedef __attribute__((ext_vector_type(8)))  short s16x8;
typedef __attribute__((ext_vector_type(4)))  short s16x4;

// B=512, T=256, E=384, H=64.

__device__ inline short f2bf(float f){
  unsigned u = __float_as_uint(f);
  u = u + 0x7fffu + ((u >> 16) & 1u);   // round-to-nearest-even
  return (short)(u >> 16);
}

// 8x f32 -> 8x bf16 via v_cvt_pk_bf16_f32 (RNE, bit-identical to f2bf)
__device__ __forceinline__ s16x8 pack8(f32x4 a0, f32x4 a1){
  union { s16x8 v; unsigned u[4]; } r;
  asm("v_cvt_pk_bf16_f32 %0, %1, %2" : "=v"(r.u[0]) : "v"(a0[0]), "v"(a0[1]));
  asm("v_cvt_pk_bf16_f32 %0, %1, %2" : "=v"(r.u[1]) : "v"(a0[2]), "v"(a0[3]));
  asm("v_cvt_pk_bf16_f32 %0, %1, %2" : "=v"(r.u[2]) : "v"(a1[0]), "v"(a1[1]));
  asm("v_cvt_pk_bf16_f32 %0, %1, %2" : "=v"(r.u[3]) : "v"(a1[2]), "v"(a1[3]));
  return r.v;
}

__device__ __forceinline__ void gld16(const void* g, void* l){
  __builtin_amdgcn_global_load_lds((const __attribute__((address_space(1))) void*)g,
                                   (__attribute__((address_space(3))) void*)l, 16, 0, 0);
}

// -------- Kernel 0a: legacy Wt[n][k] layout (fallback path only) --------
__global__ void wt_prep_kernel(const float* __restrict__ Wq, const float* __restrict__ Wk,
                               const float* __restrict__ Wv, short* __restrict__ Wt){
  int o = blockIdx.x * 256 + threadIdx.x;
  if (o >= 192*384) return;
  int n = o / 384, k = o - n*384;
  const float* W = (n < 64) ? Wq : (n < 128) ? Wk : Wv;
  Wt[o] = f2bf(W[k*64 + (n & 63)]);
}

// -------- Kernel 0b: fragment-major Wt2 --------
// 144 fragments (kt=0..11, c=0..11), each 1 KB: lane L (=quad*16+l15) holds
// 8 bf16 = W[k = kt*32+quad*8+j][col = c*16+l15]. A wave's fragment load is a
// single fully-coalesced 1 KB read (vs 32-line gather with the [n][k] layout).
__global__ void wt_prep2_kernel(const float* __restrict__ Wq, const float* __restrict__ Wk,
                                const float* __restrict__ Wv, short* __restrict__ Wt2){
  int f = blockIdx.x * 256 + threadIdx.x;     // fragment-slot id, 9216 total
  if (f >= 9216) return;
  int Bq = f >> 6, lane = f & 63;
  int kt = Bq / 12, c = Bq - kt*12;
  int col = c*16 + (lane & 15);
  int k0  = kt*32 + (lane >> 4)*8;
  const float* W = (col < 64) ? Wq : (col < 128) ? Wk : Wv;
  int cc = col & 63;
  short* dst = Wt2 + (long)f*8;
  #pragma unroll
  for (int j = 0; j < 8; ++j) dst[j] = f2bf(W[(k0 + j)*64 + cc]);
}

// -------- Kernel A: QKV projection v4 — barrier-free, wave-private pipelines --------
// 1 wave = 16 t-rows x 192 out-cols (12x 16x16x32 MFMA acc = 48 VGPR).
// x staged per-wave into PRIVATE LDS (2x2KB dbuf) via gld16 with pre-swizzled
// coalesced source; consumption gated only by the wave's own vmcnt -> the
// kernel has ZERO barriers. Wt fragments are coalesced 1KB loads from Wt2,
// issued BEFORE stage(kt+1) so their implicit register-wait is vmcnt(2) and
// never drains the prefetch. V tiles use operand-swapped MFMA so the epilogue
// emits the round-1 harness-verified Q/K/V image formats byte-for-byte:
//   Q: [b][t][h] row-major bf16
//   K: [b][t][128B row], byte = h*2 ^ ((t&7)<<4)
//   V: [b][h][512B row], byte = t*2 ^ ((h&7)<<4)
__global__ __launch_bounds__(512, 4) void qkv4_kernel(const float* __restrict__ x,
    const short* __restrict__ Wt2, short* __restrict__ Qg,
    short* __restrict__ Kg, short* __restrict__ Vg){
  __shared__ __align__(16) char xlds[8][2][2048];   // wave-private, 32 KB total

  const int tid  = threadIdx.x;
  const int w    = tid >> 6, lane = tid & 63;
  const int l15  = lane & 15, quad = lane >> 4;
  const int b    = blockIdx.x >> 1;
  const int t0   = (blockIdx.x & 1) << 7;
  const int r0   = t0 + w*16;                       // this wave's 16 rows

  const char* xbase = (const char*)x + ((long)b*256 + r0)*1536;

  // stage chunk kt (16 rows x 128 B) into private buf; LDS linear, source
  // carries the inverse swizzle (read-side XOR matches: rule #21 involution).
  auto stage = [&](int kt, int buf){
    #pragma unroll
    for (int i = 0; i < 2; ++i){
      const char* src = xbase + (long)(i*8 + (lane >> 3))*1536 + kt*128
                      + ((((lane & 7) ^ (lane >> 3))) << 4);
      gld16(src, &xlds[w][buf][i*1024]);
    }
  };

  f32x4 acc[12];
  #pragma unroll
  for (int c = 0; c < 12; ++c)
    #pragma unroll
    for (int i = 0; i < 4; ++i) acc[c][i] = 0.0f;

  const short* wlane = Wt2 + lane*8;                // per-lane fragment base
  const int xsw = (l15 & 7) << 4;

  stage(0, 0);

  #pragma unroll 2
  for (int kt = 0; kt < 12; ++kt){
    // 1) Wt fragments for this chunk — 12 coalesced 1KB loads, issued FIRST
    s16x8 wf[12];
    #pragma unroll
    for (int c = 0; c < 12; ++c)
      wf[c] = *(const s16x8*)(wlane + (kt*12 + c)*512);
    __builtin_amdgcn_sched_barrier(0);              // keep Wt issued before stage
    // 2) prefetch next x-chunk
    if (kt < 11) stage(kt + 1, (kt + 1) & 1);
    // 3) wait for own stage(kt): outstanding = stage(kt)2 + Wt12 + stage(kt+1)2
    asm volatile("s_waitcnt vmcnt(2)" ::: "memory");
    __builtin_amdgcn_sched_barrier(0);
    // 4) x fragment from private LDS
    const char* bp = &xlds[w][kt & 1][0];
    f32x4 a0 = *(const f32x4*)(bp + l15*128 + ((quad*32)      ^ xsw));
    f32x4 a1 = *(const f32x4*)(bp + l15*128 + ((quad*32 + 16) ^ xsw));
    s16x8 bx = pack8(a0, a1);
    // 5) MFMAs: Q,K normal; V operand-swapped (accumulator h-major)
    #pragma unroll
    for (int c = 0; c < 8; ++c)
      acc[c] = __builtin_amdgcn_mfma_f32_16x16x32_bf16(wf[c], bx, acc[c], 0, 0, 0);
    #pragma unroll
    for (int c = 8; c < 12; ++c)
      acc[c] = __builtin_amdgcn_mfma_f32_16x16x32_bf16(bx, wf[c], acc[c], 0, 0, 0);
  }

  // ---- epilogue. 16x16 D layout: col(n)=l15, row(m)=quad*4+i ----
  const int tr = r0 + l15;                          // t for non-swapped accs
  short* Qb = Qg + (long)b*16384;
  char*  Kb = (char*)(Kg + (long)b*16384);
  char*  Vb = (char*)(Vg + (long)b*16384);

  #pragma unroll
  for (int c = 0; c < 4; ++c){                      // Q: h = c*16 + quad*4 + i
    s16x4 v;
    #pragma unroll
    for (int i = 0; i < 4; ++i) v[i] = f2bf(acc[c][i]);
    *(s16x4*)(Qb + (long)tr*64 + c*16 + quad*4) = v;
  }
  {
    const int swk = (tr & 7) << 4;                  // K: h = (c-4)*16 + quad*4 + i
    #pragma unroll
    for (int c = 4; c < 8; ++c){
      s16x4 v;
      #pragma unroll
      for (int i = 0; i < 4; ++i) v[i] = f2bf(acc[c][i]);
      *(s16x4*)(Kb + (long)tr*128 + (((c - 4)*32 + quad*8) ^ swk)) = v;
    }
  }
  #pragma unroll
  for (int c = 8; c < 12; ++c){                     // V swapped: lane = h, regs = t
    const int h   = (c - 8)*16 + l15;
    const int swv = (h & 7) << 4;
    s16x4 v;
    #pragma unroll
    for (int i = 0; i < 4; ++i) v[i] = f2bf(acc[c][i]);
    *(s16x4*)(Vb + (long)h*512 + (((r0 + quad*4)*2) ^ swv)) = v;
  }
}

// ---------------- Kernel B: causal attention (round-1 verified) ----------------
__global__ __launch_bounds__(512, 4) void attn_kernel(const short* __restrict__ Qg,
    const short* __restrict__ Kg, const short* __restrict__ Vg,
    float* __restrict__ out){
  __shared__ __align__(16) short Ks[16384];     // 32768 B swizzled [t][h] image
  __shared__ __align__(16) short Vts[16384];    // 32768 B swizzled [h][t] image
  __shared__ __align__(16) short Pp[8][16*40];  // 10240 B per-wave P scratch

  const int tid  = threadIdx.x;
  const int w    = tid >> 6, lane = tid & 63;
  const int l15  = lane & 15, quad = lane >> 4;
  const int b    = blockIdx.x;

  const short* Qb = Qg + (long)b*16384;
  const int F0 = w, F1 = 15 - w;
  s16x8 qA0 = *(const s16x8*)(Qb + (F0*16 + l15)*64 + quad*8);
  s16x8 qA1 = *(const s16x8*)(Qb + (F0*16 + l15)*64 + 32 + quad*8);
  s16x8 qB0 = *(const s16x8*)(Qb + (F1*16 + l15)*64 + quad*8);
  s16x8 qB1 = *(const s16x8*)(Qb + (F1*16 + l15)*64 + 32 + quad*8);

  const char* Kb = (const char*)(Kg + (long)b*16384);
  const char* Vb = (const char*)(Vg + (long)b*16384);
  {
    const int base = w*4096;
    #pragma unroll
    for (int i = 0; i < 4; ++i){
      gld16(Kb + base + i*1024 + lane*16, (char*)Ks  + base + i*1024);
      gld16(Vb + base + i*1024 + lane*16, (char*)Vts + base + i*1024);
    }
  }
  __syncthreads();

  float* ob = out + (long)b*256*64;
  short* Pw = Pp[w];
  const int swz = (l15 & 7) << 4;

  auto attend = [&](int F, s16x8 qf0, s16x8 qf1){
    const int qb = F*16;
    const int NF = F + 1;
    const int NS = (NF + 1) >> 1;

    f32x4 sc[16];
    #pragma unroll
    for (int f = 0; f < 16; ++f){
      f32x4 a;
      #pragma unroll
      for (int r = 0; r < 4; ++r) a[r] = 0.0f;
      if (f < NF){
        const char* kp = (const char*)Ks + (f*16 + l15)*128;
        s16x8 k0v = *(const s16x8*)(kp + ((quad*16)      ^ swz));
        s16x8 k1v = *(const s16x8*)(kp + ((64 + quad*16) ^ swz));
        a = __builtin_amdgcn_mfma_f32_16x16x32_bf16(qf0, k0v, a, 0, 0, 0);
        a = __builtin_amdgcn_mfma_f32_16x16x32_bf16(qf1, k1v, a, 0, 0, 0);
      }
      sc[f] = a;
    }

    float mx[4], sm[4];
    #pragma unroll
    for (int r = 0; r < 4; ++r) mx[r] = -3.0e38f;
    #pragma unroll
    for (int f = 0; f < 16; ++f){
      if (f < NF){
        const int key = f*16 + l15;
        #pragma unroll
        for (int r = 0; r < 4; ++r){
          const int qg = qb + quad*4 + r;
          float s = sc[f][r] * 0.125f;
          s = (key <= qg) ? s : -1.0e30f;
          sc[f][r] = s;
          mx[r] = fmaxf(mx[r], s);
        }
      }
    }
    #pragma unroll
    for (int r = 0; r < 4; ++r){
      #pragma unroll
      for (int off = 1; off < 16; off <<= 1) mx[r] = fmaxf(mx[r], __shfl_xor(mx[r], off, 16));
    }
    #pragma unroll
    for (int r = 0; r < 4; ++r) sm[r] = 0.0f;
    #pragma unroll
    for (int f = 0; f < 16; ++f){
      if (f < NF){
        #pragma unroll
        for (int r = 0; r < 4; ++r){
          float p = exp2f((sc[f][r] - mx[r]) * 1.44269504f);
          sc[f][r] = p;
          sm[r] += p;
        }
      }
    }
    #pragma unroll
    for (int r = 0; r < 4; ++r){
      #pragma unroll
      for (int off = 1; off < 16; off <<= 1) sm[r] += __shfl_xor(sm[r], off, 16);
    }

    f32x4 o[4];
    #pragma unroll
    for (int h0 = 0; h0 < 4; ++h0)
      #pragma unroll
      for (int r = 0; r < 4; ++r) o[h0][r] = 0.0f;

    #pragma unroll
    for (int ks = 0; ks < 8; ++ks){
      if (ks < NS){
        #pragma unroll
        for (int fi = 0; fi < 2; ++fi){
          const int f = 2*ks + fi;
          #pragma unroll
          for (int r = 0; r < 4; ++r){
            short v = 0;
            if (f < NF) v = f2bf(sc[f][r]);
            Pw[(quad*4 + r)*40 + fi*16 + l15] = v;
          }
        }
        s16x8 pf = *(const s16x8*)(Pw + l15*40 + quad*8);
        #pragma unroll
        for (int h0 = 0; h0 < 4; ++h0){
          const char* vp = (const char*)Vts + (h0*16 + l15)*512;
          s16x8 vf = *(const s16x8*)(vp + ((ks*64 + quad*16) ^ swz));
          o[h0] = __builtin_amdgcn_mfma_f32_16x16x32_bf16(pf, vf, o[h0], 0, 0, 0);
        }
      }
    }

    #pragma unroll
    for (int r = 0; r < 4; ++r){
      const float inv = 1.0f / sm[r];
      #pragma unroll
      for (int h0 = 0; h0 < 4; ++h0)
        ob[(qb + quad*4 + r)*64 + h0*16 + l15] = o[h0][r] * inv;
    }
  };
  attend(F0, qA0, qA1);
  attend(F1, qB0, qB1);
}

// ---------------- Fallback (ws too small): round-2 fused kernel ----------------
__global__ __launch_bounds__(512, 4) void fused2_kernel(const float* __restrict__ x,
                             const short* __restrict__ Wt, float* __restrict__ out){
  __shared__ __align__(16) char  KsB[32768];
  __shared__ __align__(16) char  VtsB[32768];
  __shared__ __align__(16) short Pp[8][16*40];

  const int tid  = threadIdx.x;
  const int w    = tid >> 6, lane = tid & 63;
  const int l15  = lane & 15, quad = lane >> 4;
  const int b    = blockIdx.x;

  const float* xb = x + (long)b*256*384;
  const int F0 = w, F1 = 15 - w;

  s16x8 qA0, qA1, qB0, qB1;

  auto project = [&](int r0, s16x8& qf0, s16x8& qf1){
    f32x4 aq[4], ak[4], av[4];
    #pragma unroll
    for (int c = 0; c < 4; ++c)
      #pragma unroll
      for (int i = 0; i < 4; ++i){ aq[c][i]=0.f; ak[c][i]=0.f; av[c][i]=0.f; }

    const float* xr = xb + (long)(r0 + l15)*384;
    #pragma unroll 2
    for (int kt = 0; kt < 12; ++kt){
      const int k0 = kt*32 + quad*8;
      float4 a0 = *(const float4*)(xr + k0);
      float4 a1 = *(const float4*)(xr + k0 + 4);
      s16x8 bx;
      bx[0]=f2bf(a0.x); bx[1]=f2bf(a0.y); bx[2]=f2bf(a0.z); bx[3]=f2bf(a0.w);
      bx[4]=f2bf(a1.x); bx[5]=f2bf(a1.y); bx[6]=f2bf(a1.z); bx[7]=f2bf(a1.w);
      #pragma unroll
      for (int c = 0; c < 4; ++c){
        s16x8 wq = *(const s16x8*)(Wt + (c*16 + l15)*384 + k0);
        aq[c] = __builtin_amdgcn_mfma_f32_16x16x32_bf16(wq, bx, aq[c], 0, 0, 0);
      }
      #pragma unroll
      for (int c = 0; c < 4; ++c){
        s16x8 wk = *(const s16x8*)(Wt + ((c+4)*16 + l15)*384 + k0);
        ak[c] = __builtin_amdgcn_mfma_f32_16x16x32_bf16(wk, bx, ak[c], 0, 0, 0);
      }
      #pragma unroll
      for (int c = 0; c < 4; ++c){
        s16x8 wv = *(const s16x8*)(Wt + ((c+8)*16 + l15)*384 + k0);
        av[c] = __builtin_amdgcn_mfma_f32_16x16x32_bf16(bx, wv, av[c], 0, 0, 0);
      }
    }

    char* krow = KsB + (r0 + l15)*128;
    const int swzr = (l15 & 7) << 4;

    #pragma unroll
    for (int c = 0; c < 4; ++c){
      s16x4 v;
      #pragma unroll
      for (int i = 0; i < 4; ++i) v[i] = f2bf(aq[c][i]);
      *(s16x4*)(krow + ((c*32 + quad*8) ^ swzr)) = v;
    }
    asm volatile("s_waitcnt lgkmcnt(0)" ::: "memory");
    qf0 = *(const s16x8*)(krow + ((quad*16)      ^ swzr));
    qf1 = *(const s16x8*)(krow + ((64 + quad*16) ^ swzr));
    asm volatile("s_waitcnt lgkmcnt(0)" ::: "memory");

    #pragma unroll
    for (int c = 0; c < 4; ++c){
      s16x4 v;
      #pragma unroll
      for (int i = 0; i < 4; ++i) v[i] = f2bf(ak[c][i]);
      *(s16x4*)(krow + ((c*32 + quad*8) ^ swzr)) = v;
    }
    #pragma unroll
    for (int c = 0; c < 4; ++c){
      const int h = c*16 + l15;
      s16x4 v;
      #pragma unroll
      for (int i = 0; i < 4; ++i) v[i] = f2bf(av[c][i]);
      *(s16x4*)(VtsB + h*512 + (((r0 + quad*4)*2) ^ ((h & 7) << 4))) = v;
    }
  };

  project(F0*16, qA0, qA1);
  project(F1*16, qB0, qB1);

  __syncthreads();

  float* ob = out + (long)b*256*64;
  short* Pw = Pp[w];
  const int swz = (l15 & 7) << 4;

  auto attend = [&](int F, s16x8 qf0, s16x8 qf1){
    const int qb = F*16;
    const int NF = F + 1;
    const int NS = (NF + 1) >> 1;

    f32x4 sc[16];
    #pragma unroll
    for (int f = 0; f < 16; ++f){
      f32x4 a;
      #pragma unroll
      for (int r = 0; r < 4; ++r) a[r] = 0.0f;
      if (f < NF){
        const char* kp = KsB + (f*16 + l15)*128;
        s16x8 k0v = *(const s16x8*)(kp + ((quad*16)      ^ swz));
        s16x8 k1v = *(const s16x8*)(kp + ((64 + quad*16) ^ swz));
        a = __builtin_amdgcn_mfma_f32_16x16x32_bf16(qf0, k0v, a, 0, 0, 0);
        a = __builtin_amdgcn_mfma_f32_16x16x32_bf16(qf1, k1v, a, 0, 0, 0);
      }
      sc[f] = a;
    }

    float mx[4], sm[4];
    #pragma unroll
    for (int r = 0; r < 4; ++r) mx[r] = -3.0e38f;
    #pragma unroll
    for (int f = 0; f < 16; ++f){
      if (f < NF){
        const int key = f*16 + l15;
        #pragma unroll
        for (int r = 0; r < 4; ++r){
          const int qg = qb + quad*4 + r;
          float s = sc[f][r] * 0.125f;
          s = (key <= qg) ? s : -1.0e30f;
          sc[f][r] = s;
          mx[r] = fmaxf(mx[r], s);
        }
      }
    }
    #pragma unroll
    for (int r = 0; r < 4; ++r){
      #pragma unroll
      for (int off = 1; off < 16; off <<= 1) mx[r] = fmaxf(mx[r], __shfl_xor(mx[r], off, 16));
    }
    #pragma unroll
    for (int r = 0; r < 4; ++r) sm[r] = 0.0f;
    #pragma unroll
    for (int f = 0; f < 16; ++f){
      if (f < NF){
        #pragma unroll
        for (int r = 0; r < 4; ++r){
          float p = exp2f((sc[f][r] - mx[r]) * 1.44269504f);
          sc[f][r] = p;
          sm[r] += p;
        }
      }
    }
    #pragma unroll
    for (int r = 0; r < 4; ++r){
      #pragma unroll
      for (int off = 1; off < 16; off <<= 1) sm[r] += __shfl_xor(sm[r], off, 16);
    }

    f32x4 o[4];
    #pragma unroll
    for (int h0 = 0; h0 < 4; ++h0)
      #pragma unroll
      for (int r = 0; r < 4; ++r) o[h0][r] = 0.0f;

    #pragma unroll
    for (int ks = 0; ks < 8; ++ks){
      if (ks < NS){
        #pragma unroll
        for (int fi = 0; fi < 2; ++fi){
          const int f = 2*ks + fi;
          #pragma unroll
          for (int r = 0; r < 4; ++r){
            short v = 0;
            if (f < NF) v = f2bf(sc[f][r]);
            Pw[(quad*4 + r)*40 + fi*16 + l15] = v;
          }
        }
        s16x8 pf = *(const s16x8*)(Pw + l15*40 + quad*8);
        #pragma unroll
        for (int h0 = 0; h0 < 4; ++h0){
          const char* vp = VtsB + (h0*16 + l15)*512;
          s16x8 vf = *(const s16x8*)(vp + ((ks*64 + quad*16) ^ swz));
          o[h0] = __builtin_amdgcn_mfma_f32_16x16x32_bf16(pf, vf, o[h0], 0, 0, 0);
        }
      }
    }

    #pragma unroll
    for (int r = 0; r < 4; ++r){
      const float inv = 1.0f / sm[r];
      #pragma unroll
      for (int h0 = 0; h0 < 4; ++h0)
        ob[(qb + quad*4 + r)*64 + h0*16 + l15] = o[h0][r] * inv;
    }
  };

  attend(F0, qA0, qA1);
  attend(F1, qB0, qB1);
}

extern "C" void kernel_launch(void* const* d_in, const int* in_sizes, int n_in,
                              void* d_out, int out_size, void* d_ws, size_t ws_size,
                              hipStream_t stream){
  const float* x  = (const float*)d_in[0];
  const float* Wq = (const float*)d_in[1];
  const float* Wk = (const float*)d_in[2];
  const float* Wv = (const float*)d_in[3];
  float* out = (float*)d_out;

  short* Wt = (short*)d_ws;                        // 147456 B (either layout)
  const size_t need = 147456 + 3ull*16777216ull;   // Wt + Q/K/V bf16 images

  if (ws_size >= need){
    short* Qg = (short*)((char*)d_ws + 147456);
    short* Kg = Qg + 8388608;
    short* Vg = Kg + 8388608;
    hipLaunchKernelGGL(wt_prep2_kernel, dim3(36), dim3(256), 0, stream, Wq, Wk, Wv, Wt);
    hipLaunchKernelGGL(qkv4_kernel, dim3(1024), dim3(512), 0, stream, x, Wt, Qg, Kg, Vg);
    hipLaunchKernelGGL(attn_kernel, dim3(512),  dim3(512), 0, stream, Qg, Kg, Vg, out);
  } else {
    hipLaunchKernelGGL(wt_prep_kernel, dim3(288), dim3(256), 0, stream, Wq, Wk, Wv, Wt);
    hipLaunchKernelGGL(fused2_kernel, dim3(512), dim3(512), 0, stream, x, Wt, out);
  }
}